// Round 8
// baseline (151.548 us; speedup 1.0000x reference)
//
#include <hip/hip_runtime.h>
#include <math.h>

#define NSEQ   2048
#define DMODEL 1024
#define NHEADS 16
#define HD     64

typedef short bf16x8 __attribute__((ext_vector_type(8)));
typedef float f32x4  __attribute__((ext_vector_type(4)));
typedef unsigned short ushort8_t __attribute__((ext_vector_type(8)));

// RTNE float -> bf16 bits
__device__ __forceinline__ unsigned short f2bf(float x) {
    unsigned int u = __builtin_bit_cast(unsigned int, x);
    unsigned int r = (u + 0x7FFFu + ((u >> 16) & 1u)) >> 16;
    return (unsigned short)r;
}
// v_cvt_pk_bf16_f32: D[15:0]=bf16(lo), D[31:16]=bf16(hi) (RTNE)
__device__ __forceinline__ unsigned int cvt_pk_bf16(float lo, float hi) {
    unsigned int d;
    asm("v_cvt_pk_bf16_f32 %0, %1, %2" : "=v"(d) : "v"(lo), "v"(hi));
    return d;
}

// ---------------------------------------------------------------------------
// Convert inputs to bf16: x(2M)->xb, Wq/Wk/Wv(3x1M)->Wb[3072][1024], Wo->Wob.
// ---------------------------------------------------------------------------
__global__ __launch_bounds__(256) void convert_inputs(
    const float* __restrict__ x,  const float* __restrict__ Wq,
    const float* __restrict__ Wk, const float* __restrict__ Wv,
    const float* __restrict__ Wo,
    unsigned short* __restrict__ xb, unsigned short* __restrict__ Wb,
    unsigned short* __restrict__ Wob)
{
    const size_t i8 = ((size_t)blockIdx.x * 256 + threadIdx.x) * 8;
    const float* src;
    unsigned short* dst;
    if (i8 < (2ull << 20)) {
        src = x + i8;  dst = xb + i8;
    } else if (i8 < (5ull << 20)) {
        const size_t o = i8 - (2ull << 20);
        const size_t s = o >> 20;
        src = (s == 0 ? Wq : (s == 1 ? Wk : Wv)) + (o & ((1u << 20) - 1));
        dst = Wb + o;
    } else {
        const size_t o = i8 - (5ull << 20);
        src = Wo + o;  dst = Wob + o;
    }
    const float4 v0 = *reinterpret_cast<const float4*>(src);
    const float4 v1 = *reinterpret_cast<const float4*>(src + 4);
    ushort8_t r;
    r[0] = f2bf(v0.x); r[1] = f2bf(v0.y); r[2] = f2bf(v0.z); r[3] = f2bf(v0.w);
    r[4] = f2bf(v1.x); r[5] = f2bf(v1.y); r[6] = f2bf(v1.z); r[7] = f2bf(v1.w);
    *reinterpret_cast<ushort8_t*>(dst) = r;
}

// ---------------------------------------------------------------------------
// QKV GEMM (B-transposed): bf16 MFMA, fp32 acc. BM=BN=128, BK=64; 4 waves.
// cols 0-1023 (Q) / 1024-2047 (K): bf16 out + per-(head,row) norms
// (qn, cq2=2/(1-qn) | kn, ck=1/(1-kn)); cols 2048-3071 (V): bf16 out.
// ---------------------------------------------------------------------------
__global__ __launch_bounds__(256) void gemm_qkv(
    const unsigned short* __restrict__ A, const unsigned short* __restrict__ B,
    unsigned short* __restrict__ QbO, float* __restrict__ qnO,
    float* __restrict__ cq2O,
    unsigned short* __restrict__ KbO, float* __restrict__ knO,
    float* __restrict__ ckO,
    unsigned short* __restrict__ VbO)
{
    __shared__ unsigned short Ahs[128 * 72];
    __shared__ unsigned short Bhs[128 * 72];

    const int bm   = blockIdx.x * 128;
    const int bn   = blockIdx.y * 128;
    const int t    = threadIdx.x;
    const int wid  = t >> 6;
    const int lane = t & 63;
    const int g    = lane >> 4;
    const int r    = lane & 15;
    const int wm   = (wid >> 1) * 64;
    const int wn   = (wid & 1) * 64;

    f32x4 acc[4][4];
#pragma unroll
    for (int i = 0; i < 4; ++i)
#pragma unroll
        for (int j = 0; j < 4; ++j) acc[i][j] = (f32x4){0.f, 0.f, 0.f, 0.f};

    const int srow = t >> 1;
    const int sseg = (t & 1) * 32;

    for (int k0 = 0; k0 < DMODEL; k0 += 64) {
        __syncthreads();
        ushort8_t av[4], bv[4];
#pragma unroll
        for (int c = 0; c < 4; ++c) {
            av[c] = *reinterpret_cast<const ushort8_t*>(
                &A[(size_t)(bm + srow) * DMODEL + k0 + sseg + c * 8]);
            bv[c] = *reinterpret_cast<const ushort8_t*>(
                &B[(size_t)(bn + srow) * DMODEL + k0 + sseg + c * 8]);
        }
#pragma unroll
        for (int c = 0; c < 4; ++c) {
            *reinterpret_cast<ushort8_t*>(&Ahs[srow * 72 + sseg + c * 8]) = av[c];
            *reinterpret_cast<ushort8_t*>(&Bhs[srow * 72 + sseg + c * 8]) = bv[c];
        }
        __syncthreads();

#pragma unroll
        for (int dc = 0; dc < 2; ++dc) {
            bf16x8 af[4], bfr[4];
#pragma unroll
            for (int mt = 0; mt < 4; ++mt)
                af[mt] = *reinterpret_cast<const bf16x8*>(
                    &Ahs[(wm + mt * 16 + r) * 72 + dc * 32 + g * 8]);
#pragma unroll
            for (int nt = 0; nt < 4; ++nt)
                bfr[nt] = *reinterpret_cast<const bf16x8*>(
                    &Bhs[(wn + nt * 16 + r) * 72 + dc * 32 + g * 8]);
#pragma unroll
            for (int mt = 0; mt < 4; ++mt)
#pragma unroll
                for (int nt = 0; nt < 4; ++nt)
                    acc[mt][nt] = __builtin_amdgcn_mfma_f32_16x16x32_bf16(
                        af[mt], bfr[nt], acc[mt][nt], 0, 0, 0);
        }
    }

    const int sel = bn >> 10;
    const int bnl = bn & 1023;
    if (sel < 2) {
        unsigned short* Hb = sel ? KbO : QbO;
        float* narr = sel ? knO : qnO;
        float* carr = sel ? ckO : cq2O;
        const int hh = (bnl + wn) >> 6;   // one head per wave (64 cols)
#pragma unroll
        for (int mt = 0; mt < 4; ++mt) {
#pragma unroll
            for (int rg = 0; rg < 4; ++rg) {
                float ss = 0.f;
#pragma unroll
                for (int nt = 0; nt < 4; ++nt) {
                    const float v = acc[mt][nt][rg];
                    ss = fmaf(v, v, ss);
                    Hb[(size_t)(bm + wm + mt * 16 + g * 4 + rg) * 1024 +
                       bnl + wn + nt * 16 + r] = f2bf(v);
                }
                ss += __shfl_xor(ss, 1, 64);
                ss += __shfl_xor(ss, 2, 64);
                ss += __shfl_xor(ss, 4, 64);
                ss += __shfl_xor(ss, 8, 64);
                if (r == 0) {
                    const int row = bm + wm + mt * 16 + g * 4 + rg;
                    narr[hh * NSEQ + row] = ss;
                    carr[hh * NSEQ + row] = (sel ? 1.0f : 2.0f) / (1.0f - ss);
                }
            }
        }
    } else {
#pragma unroll
        for (int mt = 0; mt < 4; ++mt)
#pragma unroll
            for (int nt = 0; nt < 4; ++nt)
#pragma unroll
                for (int rg = 0; rg < 4; ++rg)
                    VbO[(size_t)(bm + wm + mt * 16 + g * 4 + rg) * 1024 +
                        bnl + wn + nt * 16 + r] = f2bf(acc[mt][nt][rg]);
    }
}

// ---------------------------------------------------------------------------
// Per-head V transpose (bf16->bf16): Vt[(h*64+d)*2048 + n] = Vb[n*1024+h*64+d]
// ---------------------------------------------------------------------------
__global__ __launch_bounds__(256) void vt_kernel_bf16(
    const unsigned short* __restrict__ Vb, unsigned short* __restrict__ Vt)
{
    __shared__ unsigned short Vs[64 * 72];
    const int h   = blockIdx.y;
    const int n0  = blockIdx.x * 64;
    const int t   = threadIdx.x;
    const int row = t >> 2;
    const int seg = (t & 3) * 16;

    const unsigned short* src = Vb + (size_t)(n0 + row) * 1024 + h * HD + seg;
    *reinterpret_cast<ushort8_t*>(&Vs[row * 72 + seg]) =
        *reinterpret_cast<const ushort8_t*>(src);
    *reinterpret_cast<ushort8_t*>(&Vs[row * 72 + seg + 8]) =
        *reinterpret_cast<const ushort8_t*>(src + 8);
    __syncthreads();

    ushort8_t a, b;
#pragma unroll
    for (int c = 0; c < 8; ++c) a[c] = Vs[(seg + c) * 72 + row];
#pragma unroll
    for (int c = 0; c < 8; ++c) b[c] = Vs[(seg + 8 + c) * 72 + row];
    unsigned short* dst = Vt + (size_t)(h * HD + row) * NSEQ + n0 + seg;
    *reinterpret_cast<ushort8_t*>(dst)     = a;
    *reinterpret_cast<ushort8_t*>(dst + 8) = b;
}

// ---------------------------------------------------------------------------
// MFMA hyperbolic attention v4 (swapped QK: S^T per-thread, q = r).
// Grid (NSEQ/64, NHEADS, 2). 4 waves; wave w: q rows [n0+16w,+16).
// sac = mfma(A=K, B=Q): D row = j-local (g*4+rg), col = q (r).
//   -> qn/cq2 are per-thread SCALARS; kn/ck are aligned float4 loads.
// P[q=r][j]: per jt the 4 weights are j-consecutive -> 2 cvt_pk + 1 b64
// swizzled write (slot' = slot ^ (r&7), same swizzle family as reads).
// PV: O[q][d] = mfma(A=P, B=V^T) -- unchanged from verified v3.
// Weights: w = ca - sqrt(ca^2-1) = exp(-acosh(ca)); clamp ca>=1 only.
// ---------------------------------------------------------------------------
__global__ __launch_bounds__(256) void hyp_attn_v4(
    const unsigned short* __restrict__ Qb, const unsigned short* __restrict__ Kb,
    const unsigned short* __restrict__ Vt,
    const float* __restrict__ qn_a, const float* __restrict__ cq2_a,
    const float* __restrict__ kn_a, const float* __restrict__ ck_a,
    float* __restrict__ Opart, float* __restrict__ lpart)
{
    __shared__ unsigned short Khs[64 * 64];   // [j][k-seg swz]
    __shared__ unsigned short Vts[64 * 64];   // [d][j-seg swz]
    __shared__ unsigned short Ps[4][16 * 64]; // per-wave [q][j-seg swz]

    const int h    = blockIdx.y;
    const int n0   = blockIdx.x * 64;
    const int jh   = blockIdx.z;
    const int t    = threadIdx.x;
    const int wid  = t >> 6;
    const int lane = t & 63;
    const int g    = lane >> 4;
    const int r    = lane & 15;
    const int qb   = n0 + wid * 16;

    // Q B-frags: Q[qb+r][k = dc*32 + g*8 + e]  (same load as v3)
    bf16x8 qf[2];
#pragma unroll
    for (int dc = 0; dc < 2; ++dc)
        qf[dc] = *reinterpret_cast<const bf16x8*>(
            Qb + (size_t)(qb + r) * DMODEL + h * HD + dc * 32 + g * 8);

    // per-thread scalars for q = qb + r
    const float qn_l = qn_a[h * NSEQ + qb + r];
    const float c2q  = cq2_a[h * NSEQ + qb + r];

    f32x4 oacc[4];
#pragma unroll
    for (int nt = 0; nt < 4; ++nt) oacc[nt] = (f32x4){0.f, 0.f, 0.f, 0.f};
    float l_acc = 0.f;

    const int srow = t >> 2;           // 0..63 (LDS row this thread fills)
    const int c0   = (t & 3) * 2;      // first of two 8-u16 col segments
    const int sw0  = (c0 ^ (srow & 7)) * 8;
    const int sw1  = ((c0 + 1) ^ (srow & 7)) * 8;
    const int sg   = (t & 3) * 16;     // global col offset (u16)
    unsigned short* Pw = &Ps[wid][0];
    char* PwB = (char*)Pw + r * 128 + 8 * (g & 1);   // P-write base (bytes)

    for (int tb = 0; tb < 16; ++tb) {
        const int j0 = jh * 1024 + tb * 64;
        __syncthreads();
        // ---- stage K and V^T tiles (vector loads, swizzled LDS writes) ----
        {
            const unsigned short* ks = Kb + (size_t)(j0 + srow) * DMODEL + h * HD + sg;
            const unsigned short* vs = Vt + (size_t)(h * HD + srow) * NSEQ + j0 + sg;
            *reinterpret_cast<ushort8_t*>(&Khs[srow * 64 + sw0]) =
                *reinterpret_cast<const ushort8_t*>(ks);
            *reinterpret_cast<ushort8_t*>(&Khs[srow * 64 + sw1]) =
                *reinterpret_cast<const ushort8_t*>(ks + 8);
            *reinterpret_cast<ushort8_t*>(&Vts[srow * 64 + sw0]) =
                *reinterpret_cast<const ushort8_t*>(vs);
            *reinterpret_cast<ushort8_t*>(&Vts[srow * 64 + sw1]) =
                *reinterpret_cast<const ushort8_t*>(vs + 8);
        }
        __syncthreads();

        // ---- S^T tiles + distance -> w -> P (cvt_pk + b64 swizzled) ----
#pragma unroll
        for (int jt = 0; jt < 4; ++jt) {
            f32x4 sac = (f32x4){0.f, 0.f, 0.f, 0.f};
#pragma unroll
            for (int dc = 0; dc < 2; ++dc) {
                const bf16x8 kb = *reinterpret_cast<const bf16x8*>(
                    &Khs[(jt * 16 + r) * 64 + ((dc * 4 + g) ^ (r & 7)) * 8]);
                sac = __builtin_amdgcn_mfma_f32_16x16x32_bf16(kb, qf[dc], sac, 0, 0, 0);
            }
            const int jbase = j0 + jt * 16 + g * 4;
            const float4 kn4 = *reinterpret_cast<const float4*>(
                &kn_a[h * NSEQ + jbase]);
            const float4 ck4 = *reinterpret_cast<const float4*>(
                &ck_a[h * NSEQ + jbase]);
            const float knv[4] = {kn4.x, kn4.y, kn4.z, kn4.w};
            const float ckv[4] = {ck4.x, ck4.y, ck4.z, ck4.w};
            float w[4];
#pragma unroll
            for (int rg = 0; rg < 4; ++rg) {
                const float dsq = fmaf(-2.f, sac[rg], qn_l + knv[rg]);
                const float ca  = fmaxf(fmaf(dsq, c2q * ckv[rg], 1.f), 1.0f);
                const float s2  = fmaf(ca, ca, -1.f);
                const float wj  = ca - __builtin_amdgcn_sqrtf(s2);
                l_acc += wj;
                w[rg] = wj;
            }
            uint2 pkd;
            pkd.x = cvt_pk_bf16(w[0], w[1]);
            pkd.y = cvt_pk_bf16(w[2], w[3]);
            // row q=r, logical slot 2jt+(g>>1), sub-offset 8(g&1)
            *reinterpret_cast<uint2*>(
                PwB + (((2 * jt + (g >> 1)) ^ (r & 7)) << 4)) = pkd;
        }
        // Pw is wave-private; per-wave DS ops are in-order -> no barrier

        // ---- PV: O[q][d] += P . V ----
#pragma unroll
        for (int kc = 0; kc < 2; ++kc) {
            const bf16x8 pa = *reinterpret_cast<const bf16x8*>(
                &Pw[r * 64 + ((kc * 4 + g) ^ (r & 7)) * 8]);   // A: m=r(q), k=j
#pragma unroll
            for (int nt = 0; nt < 4; ++nt) {
                const bf16x8 vb = *reinterpret_cast<const bf16x8*>(
                    &Vts[(nt * 16 + r) * 64 + ((kc * 4 + g) ^ (r & 7)) * 8]);
                oacc[nt] = __builtin_amdgcn_mfma_f32_16x16x32_bf16(pa, vb, oacc[nt], 0, 0, 0);
            }
        }
    }

    // ---- l reduce over g-groups (j-partition) ----
    l_acc += __shfl_xor(l_acc, 16, 64);
    l_acc += __shfl_xor(l_acc, 32, 64);

    // ---- write partials ----
    float* Op = Opart + (size_t)jh * NSEQ * DMODEL;
#pragma unroll
    for (int nt = 0; nt < 4; ++nt)
#pragma unroll
        for (int rg = 0; rg < 4; ++rg)
            Op[(size_t)(qb + g * 4 + rg) * DMODEL + h * HD + nt * 16 + r] =
                oacc[nt][rg];
    if (lane < 16)
        lpart[(jh * NHEADS + h) * NSEQ + qb + r] = l_acc;
}

// ---------------------------------------------------------------------------
// Output projection with fused merge: A[n][k] = (O0+O1)[n][k] / (l0+l1)[h(k)][n]
// (bf16-rounded), B = Wob. C = out (f32). Same verified GEMM core.
// ---------------------------------------------------------------------------
__global__ __launch_bounds__(256) void gemm_out_merge(
    const float* __restrict__ O0, const float* __restrict__ O1,
    const float* __restrict__ lp,          // [2*NHEADS][NSEQ]
    const unsigned short* __restrict__ B,  // Wob
    float* __restrict__ C)
{
    __shared__ unsigned short Ahs[128 * 72];
    __shared__ unsigned short Bhs[128 * 72];

    const int bm   = blockIdx.x * 128;
    const int bn   = blockIdx.y * 128;
    const int t    = threadIdx.x;
    const int wid  = t >> 6;
    const int lane = t & 63;
    const int g    = lane >> 4;
    const int r    = lane & 15;
    const int wm   = (wid >> 1) * 64;
    const int wn   = (wid & 1) * 64;

    f32x4 acc[4][4];
#pragma unroll
    for (int i = 0; i < 4; ++i)
#pragma unroll
        for (int j = 0; j < 4; ++j) acc[i][j] = (f32x4){0.f, 0.f, 0.f, 0.f};

    const int srow = t >> 1;
    const int sseg = (t & 1) * 32;
    const int arow = bm + srow;

    for (int k0 = 0; k0 < DMODEL; k0 += 64) {
        __syncthreads();
        // ---- A: merged O rows (one head per 32-col segment) ----
        const int hseg = (k0 + sseg) >> 6;
        const float li = __builtin_amdgcn_rcpf(
            lp[hseg * NSEQ + arow] + lp[(NHEADS + hseg) * NSEQ + arow]);
        const float* a0 = &O0[(size_t)arow * DMODEL + k0 + sseg];
        const float* a1 = &O1[(size_t)arow * DMODEL + k0 + sseg];
        unsigned int pk8[16];
#pragma unroll
        for (int c = 0; c < 8; ++c) {
            const float4 x0 = *reinterpret_cast<const float4*>(a0 + c * 4);
            const float4 y0 = *reinterpret_cast<const float4*>(a1 + c * 4);
            pk8[2 * c]     = cvt_pk_bf16((x0.x + y0.x) * li, (x0.y + y0.y) * li);
            pk8[2 * c + 1] = cvt_pk_bf16((x0.z + y0.z) * li, (x0.w + y0.w) * li);
        }
        ushort8_t bv[4];
#pragma unroll
        for (int c = 0; c < 4; ++c)
            bv[c] = *reinterpret_cast<const ushort8_t*>(
                &B[(size_t)(bn + srow) * DMODEL + k0 + sseg + c * 8]);
#pragma unroll
        for (int c = 0; c < 4; ++c) {
            uint4 w;
            w.x = pk8[4 * c]; w.y = pk8[4 * c + 1];
            w.z = pk8[4 * c + 2]; w.w = pk8[4 * c + 3];
            *reinterpret_cast<uint4*>(&Ahs[srow * 72 + sseg + c * 8]) = w;
            *reinterpret_cast<ushort8_t*>(&Bhs[srow * 72 + sseg + c * 8]) = bv[c];
        }
        __syncthreads();

#pragma unroll
        for (int dc = 0; dc < 2; ++dc) {
            bf16x8 af[4], bfr[4];
#pragma unroll
            for (int mt = 0; mt < 4; ++mt)
                af[mt] = *reinterpret_cast<const bf16x8*>(
                    &Ahs[(wm + mt * 16 + r) * 72 + dc * 32 + g * 8]);
#pragma unroll
            for (int nt = 0; nt < 4; ++nt)
                bfr[nt] = *reinterpret_cast<const bf16x8*>(
                    &Bhs[(wn + nt * 16 + r) * 72 + dc * 32 + g * 8]);
#pragma unroll
            for (int mt = 0; mt < 4; ++mt)
#pragma unroll
                for (int nt = 0; nt < 4; ++nt)
                    acc[mt][nt] = __builtin_amdgcn_mfma_f32_16x16x32_bf16(
                        af[mt], bfr[nt], acc[mt][nt], 0, 0, 0);
        }
    }

#pragma unroll
    for (int mt = 0; mt < 4; ++mt)
#pragma unroll
        for (int nt = 0; nt < 4; ++nt)
#pragma unroll
            for (int rg = 0; rg < 4; ++rg)
                C[(size_t)(bm + wm + mt * 16 + g * 4 + rg) * 1024 +
                  bn + wn + nt * 16 + r] = acc[mt][nt][rg];
}

// ---------------------------------------------------------------------------
extern "C" void kernel_launch(void* const* d_in, const int* in_sizes, int n_in,
                              void* d_out, int out_size, void* d_ws, size_t ws_size,
                              hipStream_t stream)
{
    const float* x  = (const float*)d_in[0];
    const float* Wq = (const float*)d_in[1];
    const float* Wk = (const float*)d_in[2];
    const float* Wv = (const float*)d_in[3];
    const float* Wo = (const float*)d_in[4];
    float* out = (float*)d_out;

    char* ws = (char*)d_ws;
    const size_t MB = 1048576;
    unsigned short* xb   = (unsigned short*)(ws);             // 4MB
    unsigned short* Wb   = (unsigned short*)(ws + 4  * MB);   // 6MB
    unsigned short* Wob  = (unsigned short*)(ws + 10 * MB);   // 2MB
    unsigned short* Qbuf = (unsigned short*)(ws + 12 * MB);   // 4MB
    unsigned short* Kbuf = (unsigned short*)(ws + 16 * MB);   // 4MB
    unsigned short* Vb   = (unsigned short*)(ws + 20 * MB);   // 4MB
    unsigned short* Vt   = (unsigned short*)(ws + 24 * MB);   // 4MB
    float*          qn   = (float*)(ws + 28 * MB);            // 128KB
    float*          cq2  = qn  + NHEADS * NSEQ;
    float*          kn   = cq2 + NHEADS * NSEQ;
    float*          ck   = kn  + NHEADS * NSEQ;
    float*          Opart= (float*)(ws + 29 * MB);            // 16MB
    float*          lpart= (float*)(ws + 45 * MB);            // 256KB

    const dim3 blk(256);

    // 1. fp32 -> bf16 conversions
    convert_inputs<<<3072, blk, 0, stream>>>(x, Wq, Wk, Wv, Wo, xb, Wb, Wob);

    // 2. fused QKV projection (bf16 out) + norms in epilogue
    gemm_qkv<<<dim3(NSEQ / 128, 3072 / 128), blk, 0, stream>>>(
        xb, Wb, Qbuf, qn, cq2, Kbuf, kn, ck, Vb);

    // 3. V transpose to [h*64+d][n]
    vt_kernel_bf16<<<dim3(NSEQ / 64, NHEADS), blk, 0, stream>>>(Vb, Vt);

    // 4. attention partials (j-split x2)
    hyp_attn_v4<<<dim3(NSEQ / 64, NHEADS, 2), blk, 0, stream>>>(
        Qbuf, Kbuf, Vt, qn, cq2, kn, ck, Opart, lpart);

    // 5. output projection with fused merge
    gemm_out_merge<<<dim3(NSEQ / 128, DMODEL / 128), blk, 0, stream>>>(
        Opart, Opart + (size_t)NSEQ * DMODEL, lpart, Wob, out);
}